// Round 1
// baseline (1012.112 us; speedup 1.0000x reference)
//
#include <hip/hip_runtime.h>

#define N_NODES 50000
#define N_EDGES 1200000
#define N_GRAPH 25
#define F_IN 128
#define H_DIM 64
#define NODES_PER_GRAPH 2000

// ---------------- workspace layout (float offsets) ----------------
#define OFF_H     0                      // N*64
#define OFF_HS    (OFF_H + N_NODES*64)   // N*64
#define OFF_ASRC  (OFF_HS + N_NODES*64)  // N
#define OFF_ADST  (OFF_ASRC + N_NODES)   // N
#define OFF_EX    (OFF_ADST + N_NODES)   // E  (alpha, then ex in-place)
#define OFF_CBUF  (OFF_EX + N_EDGES)     // 16 (2 used)
#define OFF_ZERO  (OFF_CBUF + 16)        // start of zeroed region
#define OFF_ACC   OFF_ZERO               // N*64
#define OFF_MENC  (OFF_ACC + N_NODES*64) // N (unsigned)
#define OFF_DEN   (OFF_MENC + N_NODES)   // N
#define OFF_END   (OFF_DEN + N_NODES)

// ---------------- embed: h = x @ W_embed + b  (N x 128 x 64) ----------------
__global__ __launch_bounds__(256) void k_embed(const float* __restrict__ x,
                                               const float* __restrict__ W,
                                               const float* __restrict__ b,
                                               float* __restrict__ h) {
    __shared__ float sW[F_IN * H_DIM];   // 32 KB
    __shared__ float sx[4][F_IN];        // 2 KB
    for (int i = threadIdx.x; i < F_IN * H_DIM; i += 256) sW[i] = W[i];
    int wave = threadIdx.x >> 6, lane = threadIdx.x & 63;
    float bj = b[lane];
    __syncthreads();
    for (int n0 = blockIdx.x * 4; n0 < N_NODES; n0 += gridDim.x * 4) {
        int n = n0 + wave;
        __syncthreads();
        if (n < N_NODES) {
            sx[wave][lane]      = x[n * F_IN + lane];
            sx[wave][lane + 64] = x[n * F_IN + 64 + lane];
        }
        __syncthreads();
        if (n < N_NODES) {
            float acc = bj;
            #pragma unroll
            for (int k = 0; k < F_IN; ++k) acc += sx[wave][k] * sW[k * H_DIM + lane];
            h[n * H_DIM + lane] = acc;
        }
    }
}

// ---------------- hs = act(hin) @ linW  (+ per-node attn scalars) ----------------
// MODE 0: hs_in read raw.  MODE 1: hs_in = relu(raw + bias_in[j]).
template <int MODE>
__global__ __launch_bounds__(256) void k_hs(const float* __restrict__ hin,
                                            const float* __restrict__ W,
                                            const float* __restrict__ bias_in,
                                            const float* __restrict__ attS,
                                            const float* __restrict__ attD,
                                            float* __restrict__ hs,
                                            float* __restrict__ asrc,
                                            float* __restrict__ adst) {
    __shared__ float sW[H_DIM * H_DIM];  // 16 KB
    __shared__ float sx[4][H_DIM];       // 1 KB
    for (int i = threadIdx.x; i < H_DIM * H_DIM; i += 256) sW[i] = W[i];
    int wave = threadIdx.x >> 6, lane = threadIdx.x & 63;
    float aS = attS[lane], aD = attD[lane];
    float bi = (MODE == 1) ? bias_in[lane] : 0.f;
    __syncthreads();
    for (int n0 = blockIdx.x * 4; n0 < N_NODES; n0 += gridDim.x * 4) {
        int n = n0 + wave;
        __syncthreads();
        if (n < N_NODES) {
            float v = hin[n * H_DIM + lane];
            if (MODE == 1) { v += bi; v = v > 0.f ? v : 0.f; }
            sx[wave][lane] = v;
        }
        __syncthreads();
        if (n < N_NODES) {
            float acc = 0.f;
            #pragma unroll
            for (int k = 0; k < H_DIM; ++k) acc += sx[wave][k] * sW[k * H_DIM + lane];
            hs[n * H_DIM + lane] = acc;
            float rs = acc * aS, rd = acc * aD;
            #pragma unroll
            for (int m = 1; m < 64; m <<= 1) {
                rs += __shfl_xor(rs, m);
                rd += __shfl_xor(rd, m);
            }
            if (lane == 0) { asrc[n] = rs; adst[n] = rd; }
        }
    }
}

// ---------------- per-layer edge coefficient c[l] = dot(lin_edge_W[l], att_edge[l]) ----
__global__ void k_edgecoef(const float* __restrict__ linE,
                           const float* __restrict__ attE,
                           float* __restrict__ cbuf) {
    int l = threadIdx.x >> 6, j = threadIdx.x & 63;
    float v = linE[l * 64 + j] * attE[l * 64 + j];
    #pragma unroll
    for (int m = 1; m < 64; m <<= 1) v += __shfl_xor(v, m);
    if (j == 0) cbuf[l] = v;
}

// ---------------- pass A: alpha + segment max (encoded atomicMax) ----------------
__device__ __forceinline__ unsigned enc_f(float f) {
    unsigned u = __float_as_uint(f);
    return (u & 0x80000000u) ? ~u : (u | 0x80000000u);
}
__device__ __forceinline__ float dec_f(unsigned e) {
    return __uint_as_float((e & 0x80000000u) ? (e & 0x7FFFFFFFu) : ~e);
}

__global__ __launch_bounds__(256) void k_alpha(const int* __restrict__ ei,
                                               const float* __restrict__ ea,
                                               const float* __restrict__ asrc,
                                               const float* __restrict__ adst,
                                               const float* __restrict__ cbuf,
                                               int layer,
                                               float* __restrict__ albuf,
                                               unsigned* __restrict__ menc) {
    int e = blockIdx.x * 256 + threadIdx.x;
    if (e >= N_EDGES) return;
    int s = ei[e], d = ei[N_EDGES + e];
    float a = asrc[s] + adst[d] + cbuf[layer] * ea[e];
    a = a >= 0.f ? a : 0.2f * a;
    albuf[e] = a;
    atomicMax(menc + d, enc_f(a));
}

// ---------------- pass B: ex = exp(alpha - m[dst]); denom += ex ----------------
__global__ __launch_bounds__(256) void k_exp(const int* __restrict__ ei,
                                             float* __restrict__ albuf,
                                             const unsigned* __restrict__ menc,
                                             float* __restrict__ den) {
    int e = blockIdx.x * 256 + threadIdx.x;
    if (e >= N_EDGES) return;
    int d = ei[N_EDGES + e];
    float ex = expf(albuf[e] - dec_f(menc[d]));
    albuf[e] = ex;
    atomicAdd(den + d, ex);
}

// ---------------- pass C: acc[dst] += (ex/denom) * hs[src]  (wave per edge) ----------
__global__ __launch_bounds__(256) void k_scatter(const int* __restrict__ ei,
                                                 const float* __restrict__ exbuf,
                                                 const float* __restrict__ den,
                                                 const float* __restrict__ hs,
                                                 float* __restrict__ acc) {
    int wid = (blockIdx.x * 256 + threadIdx.x) >> 6;
    int lane = threadIdx.x & 63;
    if (wid >= N_EDGES) return;
    int s = ei[wid], d = ei[N_EDGES + wid];
    float w = exbuf[wid] / (den[d] + 1e-16f);
    atomicAdd(acc + d * H_DIM + lane, w * hs[s * H_DIM + lane]);
}

// ---------------- pooling + head (one block per graph) ----------------
__global__ __launch_bounds__(256) void k_head(const float* __restrict__ acc,
                                              const float* __restrict__ gbias,
                                              const float* __restrict__ gf,
                                              const float* __restrict__ Wg,
                                              const float* __restrict__ bg,
                                              const float* __restrict__ Wc,
                                              const float* __restrict__ bc,
                                              const float* __restrict__ Wo,
                                              const float* __restrict__ bo,
                                              float* __restrict__ out) {
    int g = blockIdx.x;
    __shared__ float spart[4][64];
    __shared__ float sgraph[64];
    __shared__ float sgf[64];
    int wave = threadIdx.x >> 6, lane = threadIdx.x & 63;
    float b1 = gbias[lane];
    float sum = 0.f;
    int base = g * NODES_PER_GRAPH;
    for (int i = wave; i < NODES_PER_GRAPH; i += 4) {
        float v = acc[(size_t)(base + i) * H_DIM + lane] + b1;
        sum += v > 0.f ? v : 0.f;
    }
    spart[wave][lane] = sum;
    __syncthreads();
    if (wave == 0) {
        float tot = spart[0][lane] + spart[1][lane] + spart[2][lane] + spart[3][lane];
        sgraph[lane] = tot / (float)NODES_PER_GRAPH;
        float gv = bg[lane];
        #pragma unroll
        for (int k = 0; k < 6; ++k) gv += gf[g * 6 + k] * Wg[k * 64 + lane];
        sgf[lane] = gv;
    }
    __syncthreads();
    if (wave == 0) {
        float cj = bc[lane];
        #pragma unroll
        for (int k = 0; k < 64; ++k) cj += sgraph[k] * Wc[k * 64 + lane];
        #pragma unroll
        for (int k = 0; k < 64; ++k) cj += sgf[k] * Wc[(64 + k) * 64 + lane];
        cj = cj > 0.f ? cj : 0.f;
        float o = cj * Wo[lane];
        #pragma unroll
        for (int m = 1; m < 64; m <<= 1) o += __shfl_xor(o, m);
        if (lane == 0) out[g] = o + bo[0];
    }
}

extern "C" void kernel_launch(void* const* d_in, const int* in_sizes, int n_in,
                              void* d_out, int out_size, void* d_ws, size_t ws_size,
                              hipStream_t stream) {
    const float* x        = (const float*)d_in[0];
    const float* ea       = (const float*)d_in[1];
    const float* gf       = (const float*)d_in[2];
    const int*   ei       = (const int*)d_in[3];
    const float* W_embed  = (const float*)d_in[5];
    const float* b_embed  = (const float*)d_in[6];
    const float* W_glob   = (const float*)d_in[7];
    const float* b_glob   = (const float*)d_in[8];
    const float* lin_W    = (const float*)d_in[9];
    const float* att_src  = (const float*)d_in[10];
    const float* att_dst  = (const float*)d_in[11];
    const float* lin_eW   = (const float*)d_in[12];
    const float* att_edge = (const float*)d_in[13];
    const float* gat_bias = (const float*)d_in[14];
    const float* W_comb   = (const float*)d_in[15];
    const float* b_comb   = (const float*)d_in[16];
    const float* W_out    = (const float*)d_in[17];
    const float* b_out    = (const float*)d_in[18];
    float* out = (float*)d_out;
    float* ws  = (float*)d_ws;

    float*    h     = ws + OFF_H;
    float*    hs    = ws + OFF_HS;
    float*    asrc  = ws + OFF_ASRC;
    float*    adst  = ws + OFF_ADST;
    float*    exbuf = ws + OFF_EX;
    float*    cbuf  = ws + OFF_CBUF;
    float*    acc   = ws + OFF_ACC;
    unsigned* menc  = (unsigned*)(ws + OFF_MENC);
    float*    den   = ws + OFF_DEN;

    k_embed<<<2560, 256, 0, stream>>>(x, W_embed, b_embed, h);
    k_edgecoef<<<1, 128, 0, stream>>>(lin_eW, att_edge, cbuf);

    const int egrid = (N_EDGES + 255) / 256;
    const int sgrid = (N_EDGES * 64) / 256;

    for (int l = 0; l < 2; ++l) {
        if (l == 0)
            k_hs<0><<<2560, 256, 0, stream>>>(h, lin_W, nullptr,
                                              att_src, att_dst, hs, asrc, adst);
        else
            k_hs<1><<<2560, 256, 0, stream>>>(acc, lin_W + 64 * 64, gat_bias,
                                              att_src + 64, att_dst + 64, hs, asrc, adst);
        // zero acc / menc / den (contiguous region)
        hipMemsetAsync(ws + OFF_ZERO, 0, (size_t)(OFF_END - OFF_ZERO) * sizeof(float), stream);
        k_alpha<<<egrid, 256, 0, stream>>>(ei, ea, asrc, adst, cbuf, l, exbuf, menc);
        k_exp<<<egrid, 256, 0, stream>>>(ei, exbuf, menc, den);
        k_scatter<<<sgrid, 256, 0, stream>>>(ei, exbuf, den, hs, acc);
    }

    k_head<<<N_GRAPH, 256, 0, stream>>>(acc, gat_bias + 64, gf, W_glob, b_glob,
                                        W_comb, b_comb, W_out, b_out, out);
}

// Round 2
// 530.519 us; speedup vs baseline: 1.9078x; 1.9078x over previous
//
#include <hip/hip_runtime.h>
#include <math.h>

#define N_NODES 50000
#define N_EDGES 1200000
#define N_GRAPH 25
#define F_IN 128
#define H_DIM 64
#define NODES_PER_GRAPH 2000
#define NB_SCAN ((N_NODES + 255) / 256)   // 196

// ---------------- workspace layout (float/int offsets, 4B units) ----------------
#define OFF_H     0                        // N*64 f
#define OFF_HS    (OFF_H + N_NODES*64)     // N*64 f
#define OFF_ASRC  (OFF_HS + N_NODES*64)    // N f
#define OFF_ADST  (OFF_ASRC + N_NODES)     // N f
#define OFF_CBUF  (OFF_ADST + N_NODES)     // 16 f
#define OFF_CNT   (OFF_CBUF + 16)          // N+1 i  (zeroed each call)
#define OFF_ROWP  (OFF_CNT + N_NODES + 1)  // N+1 i
#define OFF_CUR   (OFF_ROWP + N_NODES + 1) // N i
#define OFF_BSUM  (OFF_CUR + N_NODES)      // 256 i
#define OFF_SSRT  (OFF_BSUM + 256)         // E i   (src sorted by dst)
#define OFF_EASRT (OFF_SSRT + N_EDGES)     // E f   (edge_attr sorted by dst)
#define OFF_END   (OFF_EASRT + N_EDGES)

// ---------------- embed: h = x @ W_embed + b  (N x 128 x 64) ----------------
__global__ __launch_bounds__(256) void k_embed(const float* __restrict__ x,
                                               const float* __restrict__ W,
                                               const float* __restrict__ b,
                                               float* __restrict__ h) {
    __shared__ float sW[F_IN * H_DIM];   // 32 KB
    __shared__ float sx[4][F_IN];
    for (int i = threadIdx.x; i < F_IN * H_DIM; i += 256) sW[i] = W[i];
    int wave = threadIdx.x >> 6, lane = threadIdx.x & 63;
    float bj = b[lane];
    __syncthreads();
    for (int n0 = blockIdx.x * 4; n0 < N_NODES; n0 += gridDim.x * 4) {
        int n = n0 + wave;
        __syncthreads();
        if (n < N_NODES) {
            sx[wave][lane]      = x[n * F_IN + lane];
            sx[wave][lane + 64] = x[n * F_IN + 64 + lane];
        }
        __syncthreads();
        if (n < N_NODES) {
            float acc = bj;
            #pragma unroll
            for (int k = 0; k < F_IN; ++k) acc += sx[wave][k] * sW[k * H_DIM + lane];
            h[n * H_DIM + lane] = acc;
        }
    }
}

// ---------------- hs = hin @ linW  (+ per-node attn scalars) ----------------
__global__ __launch_bounds__(256) void k_hs(const float* __restrict__ hin,
                                            const float* __restrict__ W,
                                            const float* __restrict__ attS,
                                            const float* __restrict__ attD,
                                            float* __restrict__ hs,
                                            float* __restrict__ asrc,
                                            float* __restrict__ adst) {
    __shared__ float sW[H_DIM * H_DIM];  // 16 KB
    __shared__ float sx[4][H_DIM];
    for (int i = threadIdx.x; i < H_DIM * H_DIM; i += 256) sW[i] = W[i];
    int wave = threadIdx.x >> 6, lane = threadIdx.x & 63;
    float aS = attS[lane], aD = attD[lane];
    __syncthreads();
    for (int n0 = blockIdx.x * 4; n0 < N_NODES; n0 += gridDim.x * 4) {
        int n = n0 + wave;
        __syncthreads();
        if (n < N_NODES) sx[wave][lane] = hin[n * H_DIM + lane];
        __syncthreads();
        if (n < N_NODES) {
            float acc = 0.f;
            #pragma unroll
            for (int k = 0; k < H_DIM; ++k) acc += sx[wave][k] * sW[k * H_DIM + lane];
            hs[n * H_DIM + lane] = acc;
            float rs = acc * aS, rd = acc * aD;
            #pragma unroll
            for (int m = 1; m < 64; m <<= 1) {
                rs += __shfl_xor(rs, m);
                rd += __shfl_xor(rd, m);
            }
            if (lane == 0) { asrc[n] = rs; adst[n] = rd; }
        }
    }
}

// ---------------- per-layer edge coefficient ----------------
__global__ void k_edgecoef(const float* __restrict__ linE,
                           const float* __restrict__ attE,
                           float* __restrict__ cbuf) {
    int l = threadIdx.x >> 6, j = threadIdx.x & 63;
    float v = linE[l * 64 + j] * attE[l * 64 + j];
    #pragma unroll
    for (int m = 1; m < 64; m <<= 1) v += __shfl_xor(v, m);
    if (j == 0) cbuf[l] = v;
}

// ---------------- CSR build: histogram ----------------
__global__ __launch_bounds__(256) void k_hist(const int* __restrict__ ei,
                                              int* __restrict__ cnt) {
    int e = blockIdx.x * 256 + threadIdx.x;
    if (e >= N_EDGES) return;
    atomicAdd(cnt + ei[N_EDGES + e], 1);
}

// ---------------- CSR build: scan (3 small kernels) ----------------
__device__ __forceinline__ int block_excl_scan(int v, int tid, int* lds, int* total) {
    int lane = tid & 63, w = tid >> 6;
    int incl = v;
    #pragma unroll
    for (int off = 1; off < 64; off <<= 1) {
        int t = __shfl_up(incl, off);
        if (lane >= off) incl += t;
    }
    if (lane == 63) lds[w] = incl;
    __syncthreads();
    int wo = 0;
    for (int i = 0; i < w; ++i) wo += lds[i];
    *total = lds[0] + lds[1] + lds[2] + lds[3];
    __syncthreads();
    return wo + incl - v;
}

__global__ __launch_bounds__(256) void k_scan1(const int* __restrict__ cnt,
                                               int* __restrict__ rowp,
                                               int* __restrict__ bsum) {
    __shared__ int lds[4];
    int i = blockIdx.x * 256 + threadIdx.x;
    int v = (i < N_NODES) ? cnt[i] : 0;
    int total;
    int ex = block_excl_scan(v, threadIdx.x, lds, &total);
    if (i < N_NODES) rowp[i] = ex;
    if (threadIdx.x == 0) bsum[blockIdx.x] = total;
}

__global__ __launch_bounds__(256) void k_scan2(int* __restrict__ bsum) {
    __shared__ int lds[4];
    int v = (threadIdx.x < NB_SCAN) ? bsum[threadIdx.x] : 0;
    int total;
    int ex = block_excl_scan(v, threadIdx.x, lds, &total);
    if (threadIdx.x < NB_SCAN) bsum[threadIdx.x] = ex;
}

__global__ __launch_bounds__(256) void k_scan3(int* __restrict__ rowp,
                                               const int* __restrict__ bsum,
                                               int* __restrict__ cur) {
    int i = blockIdx.x * 256 + threadIdx.x;
    if (i < N_NODES) {
        int r = rowp[i] + bsum[blockIdx.x];
        rowp[i] = r;
        cur[i] = r;
    }
    if (i == 0) rowp[N_NODES] = N_EDGES;
}

// ---------------- CSR build: fill ----------------
__global__ __launch_bounds__(256) void k_fill(const int* __restrict__ ei,
                                              const float* __restrict__ ea,
                                              int* __restrict__ cur,
                                              int* __restrict__ s_srt,
                                              float* __restrict__ ea_srt) {
    int e = blockIdx.x * 256 + threadIdx.x;
    if (e >= N_EDGES) return;
    int s = ei[e], d = ei[N_EDGES + e];
    int pos = atomicAdd(cur + d, 1);
    s_srt[pos] = s;
    ea_srt[pos] = ea[e];
}

// ---------------- fused GAT layer: per-dst online softmax + message accum ----------
__global__ __launch_bounds__(256) void k_fused(const int* __restrict__ rowp,
                                               const int* __restrict__ s_srt,
                                               const float* __restrict__ ea_srt,
                                               const float* __restrict__ asrc,
                                               const float* __restrict__ adst,
                                               const float* __restrict__ hs,
                                               const float* __restrict__ cbuf,
                                               int layer,
                                               const float* __restrict__ gbias,
                                               float* __restrict__ hout) {
    int wid = (blockIdx.x * 256 + threadIdx.x) >> 6;
    int lane = threadIdx.x & 63;
    if (wid >= N_NODES) return;
    int beg = rowp[wid], end = rowp[wid + 1];
    float adv = adst[wid];
    float c = cbuf[layer];
    float m = -INFINITY, sum = 0.f, acc = 0.f;

    for (int base = beg; base < end; base += 64) {
        int idx = base + lane;
        bool ok = idx < end;
        int s = ok ? s_srt[idx] : 0;
        float a;
        if (ok) {
            a = asrc[s] + adv + c * ea_srt[idx];
            a = a >= 0.f ? a : 0.2f * a;
        } else {
            a = -INFINITY;
        }
        // chunk max
        float cm = a;
        #pragma unroll
        for (int o = 1; o < 64; o <<= 1) cm = fmaxf(cm, __shfl_xor(cm, o));
        float newm = fmaxf(m, cm);
        float scale = __expf(m - newm);   // 0 on first chunk (m=-inf)
        sum *= scale;
        acc *= scale;
        m = newm;
        float ex = ok ? __expf(a - m) : 0.f;
        float cs = ex;
        #pragma unroll
        for (int o = 1; o < 64; o <<= 1) cs += __shfl_xor(cs, o);
        sum += cs;
        int lim = end - base; if (lim > 64) lim = 64;
        for (int i = 0; i < lim; ++i) {
            float w = __shfl(ex, i);
            int si = __shfl(s, i);
            acc += w * hs[si * H_DIM + lane];
        }
    }
    float val = acc / (sum + 1e-16f) + gbias[layer * H_DIM + lane];
    hout[wid * H_DIM + lane] = val > 0.f ? val : 0.f;
}

// ---------------- pooling + head (one block per graph) ----------------
__global__ __launch_bounds__(256) void k_head(const float* __restrict__ h,
                                              const float* __restrict__ gf,
                                              const float* __restrict__ Wg,
                                              const float* __restrict__ bg,
                                              const float* __restrict__ Wc,
                                              const float* __restrict__ bc,
                                              const float* __restrict__ Wo,
                                              const float* __restrict__ bo,
                                              float* __restrict__ out) {
    int g = blockIdx.x;
    __shared__ float spart[4][64];
    __shared__ float sgraph[64];
    __shared__ float sgf[64];
    int wave = threadIdx.x >> 6, lane = threadIdx.x & 63;
    float sum = 0.f;
    int base = g * NODES_PER_GRAPH;
    for (int i = wave; i < NODES_PER_GRAPH; i += 4)
        sum += h[(size_t)(base + i) * H_DIM + lane];
    spart[wave][lane] = sum;
    __syncthreads();
    if (wave == 0) {
        float tot = spart[0][lane] + spart[1][lane] + spart[2][lane] + spart[3][lane];
        sgraph[lane] = tot / (float)NODES_PER_GRAPH;
        float gv = bg[lane];
        #pragma unroll
        for (int k = 0; k < 6; ++k) gv += gf[g * 6 + k] * Wg[k * 64 + lane];
        sgf[lane] = gv;
    }
    __syncthreads();
    if (wave == 0) {
        float cj = bc[lane];
        #pragma unroll
        for (int k = 0; k < 64; ++k) cj += sgraph[k] * Wc[k * 64 + lane];
        #pragma unroll
        for (int k = 0; k < 64; ++k) cj += sgf[k] * Wc[(64 + k) * 64 + lane];
        cj = cj > 0.f ? cj : 0.f;
        float o = cj * Wo[lane];
        #pragma unroll
        for (int m = 1; m < 64; m <<= 1) o += __shfl_xor(o, m);
        if (lane == 0) out[g] = o + bo[0];
    }
}

extern "C" void kernel_launch(void* const* d_in, const int* in_sizes, int n_in,
                              void* d_out, int out_size, void* d_ws, size_t ws_size,
                              hipStream_t stream) {
    const float* x        = (const float*)d_in[0];
    const float* ea       = (const float*)d_in[1];
    const float* gf       = (const float*)d_in[2];
    const int*   ei       = (const int*)d_in[3];
    const float* W_embed  = (const float*)d_in[5];
    const float* b_embed  = (const float*)d_in[6];
    const float* W_glob   = (const float*)d_in[7];
    const float* b_glob   = (const float*)d_in[8];
    const float* lin_W    = (const float*)d_in[9];
    const float* att_src  = (const float*)d_in[10];
    const float* att_dst  = (const float*)d_in[11];
    const float* lin_eW   = (const float*)d_in[12];
    const float* att_edge = (const float*)d_in[13];
    const float* gat_bias = (const float*)d_in[14];
    const float* W_comb   = (const float*)d_in[15];
    const float* b_comb   = (const float*)d_in[16];
    const float* W_out    = (const float*)d_in[17];
    const float* b_out    = (const float*)d_in[18];
    float* out = (float*)d_out;
    float* ws  = (float*)d_ws;

    float* h      = ws + OFF_H;
    float* hs     = ws + OFF_HS;
    float* asrc   = ws + OFF_ASRC;
    float* adst   = ws + OFF_ADST;
    float* cbuf   = ws + OFF_CBUF;
    int*   cnt    = (int*)(ws + OFF_CNT);
    int*   rowp   = (int*)(ws + OFF_ROWP);
    int*   cur    = (int*)(ws + OFF_CUR);
    int*   bsum   = (int*)(ws + OFF_BSUM);
    int*   s_srt  = (int*)(ws + OFF_SSRT);
    float* ea_srt = ws + OFF_EASRT;

    const int egrid = (N_EDGES + 255) / 256;

    hipMemsetAsync(cnt, 0, (size_t)(N_NODES + 1) * sizeof(int), stream);
    k_embed<<<2560, 256, 0, stream>>>(x, W_embed, b_embed, h);
    k_edgecoef<<<1, 128, 0, stream>>>(lin_eW, att_edge, cbuf);

    // CSR by dst
    k_hist<<<egrid, 256, 0, stream>>>(ei, cnt);
    k_scan1<<<NB_SCAN, 256, 0, stream>>>(cnt, rowp, bsum);
    k_scan2<<<1, 256, 0, stream>>>(bsum);
    k_scan3<<<NB_SCAN, 256, 0, stream>>>(rowp, bsum, cur);
    k_fill<<<egrid, 256, 0, stream>>>(ei, ea, cur, s_srt, ea_srt);

    for (int l = 0; l < 2; ++l) {
        k_hs<<<2560, 256, 0, stream>>>(h, lin_W + l * 64 * 64,
                                       att_src + l * 64, att_dst + l * 64,
                                       hs, asrc, adst);
        k_fused<<<(N_NODES + 3) / 4, 256, 0, stream>>>(rowp, s_srt, ea_srt,
                                                       asrc, adst, hs, cbuf, l,
                                                       gat_bias, h);
    }

    k_head<<<N_GRAPH, 256, 0, stream>>>(h, gf, W_glob, b_glob,
                                        W_comb, b_comb, W_out, b_out, out);
}

// Round 3
// 423.187 us; speedup vs baseline: 2.3916x; 1.2536x over previous
//
#include <hip/hip_runtime.h>
#include <math.h>

#define N_NODES 50000
#define N_EDGES 1200000
#define N_GRAPH 25
#define F_IN 128
#define H_DIM 64
#define NODES_PER_GRAPH 2000
#define NB_SCAN ((N_NODES + 255) / 256)   // 196
#define POOL_CHUNKS 32                    // blocks per graph in k_pool

// ---------------- workspace layout (float/int offsets, 4B units) ----------------
#define OFF_H     0                        // N*64 f
#define OFF_HS    (OFF_H + N_NODES*64)     // N*64 f
#define OFF_ASRC  (OFF_HS + N_NODES*64)    // N f
#define OFF_ADST  (OFF_ASRC + N_NODES)     // N f
#define OFF_CBUF  (OFF_ADST + N_NODES)     // 16 f
#define OFF_ZERO  (OFF_CBUF + 16)          // zeroed region start
#define OFF_CNT   OFF_ZERO                 // N+1 i
#define OFF_GSUM  (OFF_CNT + N_NODES + 1)  // G*64 f
#define OFF_ZEND  (OFF_GSUM + N_GRAPH*64)
#define OFF_ROWP  OFF_ZEND                 // N+1 i
#define OFF_CUR   (OFF_ROWP + N_NODES + 1) // N i
#define OFF_BSUM  (OFF_CUR + N_NODES)      // 256 i
#define OFF_SSRT  (OFF_BSUM + 256)         // E i   (src sorted by dst)
#define OFF_EASRT (OFF_SSRT + N_EDGES)     // E f   (edge_attr sorted by dst)
#define OFF_END   (OFF_EASRT + N_EDGES)

// ---------------- embed: h = x @ W_embed + b  (N x 128 x 64) ----------------
__global__ __launch_bounds__(256) void k_embed(const float* __restrict__ x,
                                               const float* __restrict__ W,
                                               const float* __restrict__ b,
                                               float* __restrict__ h) {
    __shared__ float sW[F_IN * H_DIM];   // 32 KB
    __shared__ float sx[4][F_IN];
    for (int i = threadIdx.x; i < F_IN * H_DIM; i += 256) sW[i] = W[i];
    int wave = threadIdx.x >> 6, lane = threadIdx.x & 63;
    float bj = b[lane];
    __syncthreads();
    for (int n0 = blockIdx.x * 4; n0 < N_NODES; n0 += gridDim.x * 4) {
        int n = n0 + wave;
        __syncthreads();
        if (n < N_NODES) {
            sx[wave][lane]      = x[n * F_IN + lane];
            sx[wave][lane + 64] = x[n * F_IN + 64 + lane];
        }
        __syncthreads();
        if (n < N_NODES) {
            float acc = bj;
            #pragma unroll
            for (int k = 0; k < F_IN; ++k) acc += sx[wave][k] * sW[k * H_DIM + lane];
            h[n * H_DIM + lane] = acc;
        }
    }
}

// ---------------- hs = hin @ linW  (+ per-node attn scalars) ----------------
__global__ __launch_bounds__(256) void k_hs(const float* __restrict__ hin,
                                            const float* __restrict__ W,
                                            const float* __restrict__ attS,
                                            const float* __restrict__ attD,
                                            float* __restrict__ hs,
                                            float* __restrict__ asrc,
                                            float* __restrict__ adst) {
    __shared__ float sW[H_DIM * H_DIM];  // 16 KB
    __shared__ float sx[4][H_DIM];
    for (int i = threadIdx.x; i < H_DIM * H_DIM; i += 256) sW[i] = W[i];
    int wave = threadIdx.x >> 6, lane = threadIdx.x & 63;
    float aS = attS[lane], aD = attD[lane];
    __syncthreads();
    for (int n0 = blockIdx.x * 4; n0 < N_NODES; n0 += gridDim.x * 4) {
        int n = n0 + wave;
        __syncthreads();
        if (n < N_NODES) sx[wave][lane] = hin[n * H_DIM + lane];
        __syncthreads();
        if (n < N_NODES) {
            float acc = 0.f;
            #pragma unroll
            for (int k = 0; k < H_DIM; ++k) acc += sx[wave][k] * sW[k * H_DIM + lane];
            hs[n * H_DIM + lane] = acc;
            float rs = acc * aS, rd = acc * aD;
            #pragma unroll
            for (int m = 1; m < 64; m <<= 1) {
                rs += __shfl_xor(rs, m);
                rd += __shfl_xor(rd, m);
            }
            if (lane == 0) { asrc[n] = rs; adst[n] = rd; }
        }
    }
}

// ---------------- per-layer edge coefficient ----------------
__global__ void k_edgecoef(const float* __restrict__ linE,
                           const float* __restrict__ attE,
                           float* __restrict__ cbuf) {
    int l = threadIdx.x >> 6, j = threadIdx.x & 63;
    float v = linE[l * 64 + j] * attE[l * 64 + j];
    #pragma unroll
    for (int m = 1; m < 64; m <<= 1) v += __shfl_xor(v, m);
    if (j == 0) cbuf[l] = v;
}

// ---------------- CSR build: histogram ----------------
__global__ __launch_bounds__(256) void k_hist(const int* __restrict__ ei,
                                              int* __restrict__ cnt) {
    int e = blockIdx.x * 256 + threadIdx.x;
    if (e >= N_EDGES) return;
    atomicAdd(cnt + ei[N_EDGES + e], 1);
}

// ---------------- CSR build: scan (3 small kernels) ----------------
__device__ __forceinline__ int block_excl_scan(int v, int tid, int* lds, int* total) {
    int lane = tid & 63, w = tid >> 6;
    int incl = v;
    #pragma unroll
    for (int off = 1; off < 64; off <<= 1) {
        int t = __shfl_up(incl, off);
        if (lane >= off) incl += t;
    }
    if (lane == 63) lds[w] = incl;
    __syncthreads();
    int wo = 0;
    for (int i = 0; i < w; ++i) wo += lds[i];
    *total = lds[0] + lds[1] + lds[2] + lds[3];
    __syncthreads();
    return wo + incl - v;
}

__global__ __launch_bounds__(256) void k_scan1(const int* __restrict__ cnt,
                                               int* __restrict__ rowp,
                                               int* __restrict__ bsum) {
    __shared__ int lds[4];
    int i = blockIdx.x * 256 + threadIdx.x;
    int v = (i < N_NODES) ? cnt[i] : 0;
    int total;
    int ex = block_excl_scan(v, threadIdx.x, lds, &total);
    if (i < N_NODES) rowp[i] = ex;
    if (threadIdx.x == 0) bsum[blockIdx.x] = total;
}

__global__ __launch_bounds__(256) void k_scan2(int* __restrict__ bsum) {
    __shared__ int lds[4];
    int v = (threadIdx.x < NB_SCAN) ? bsum[threadIdx.x] : 0;
    int total;
    int ex = block_excl_scan(v, threadIdx.x, lds, &total);
    if (threadIdx.x < NB_SCAN) bsum[threadIdx.x] = ex;
}

__global__ __launch_bounds__(256) void k_scan3(int* __restrict__ rowp,
                                               const int* __restrict__ bsum,
                                               int* __restrict__ cur) {
    int i = blockIdx.x * 256 + threadIdx.x;
    if (i < N_NODES) {
        int r = rowp[i] + bsum[blockIdx.x];
        rowp[i] = r;
        cur[i] = r;
    }
    if (i == 0) rowp[N_NODES] = N_EDGES;
}

// ---------------- CSR build: fill ----------------
__global__ __launch_bounds__(256) void k_fill(const int* __restrict__ ei,
                                              const float* __restrict__ ea,
                                              int* __restrict__ cur,
                                              int* __restrict__ s_srt,
                                              float* __restrict__ ea_srt) {
    int e = blockIdx.x * 256 + threadIdx.x;
    if (e >= N_EDGES) return;
    int s = ei[e], d = ei[N_EDGES + e];
    int pos = atomicAdd(cur + d, 1);
    s_srt[pos] = s;
    ea_srt[pos] = ea[e];
}

// ---------------- fused GAT layer: per-dst online softmax + message accum ----------
__global__ __launch_bounds__(256) void k_fused(const int* __restrict__ rowp,
                                               const int* __restrict__ s_srt,
                                               const float* __restrict__ ea_srt,
                                               const float* __restrict__ asrc,
                                               const float* __restrict__ adst,
                                               const float* __restrict__ hs,
                                               const float* __restrict__ cbuf,
                                               int layer,
                                               const float* __restrict__ gbias,
                                               float* __restrict__ hout) {
    int wid = (blockIdx.x * 256 + threadIdx.x) >> 6;
    int lane = threadIdx.x & 63;
    if (wid >= N_NODES) return;
    int beg = rowp[wid], end = rowp[wid + 1];
    float adv = adst[wid];
    float c = cbuf[layer];
    float m = -INFINITY, sum = 0.f, acc = 0.f;

    for (int base = beg; base < end; base += 64) {
        int idx = base + lane;
        bool ok = idx < end;
        int s = ok ? s_srt[idx] : 0;
        float a;
        if (ok) {
            a = asrc[s] + adv + c * ea_srt[idx];
            a = a >= 0.f ? a : 0.2f * a;
        } else {
            a = -INFINITY;
        }
        float cm = a;
        #pragma unroll
        for (int o = 1; o < 64; o <<= 1) cm = fmaxf(cm, __shfl_xor(cm, o));
        float newm = fmaxf(m, cm);
        float scale = __expf(m - newm);   // 0 on first chunk (m=-inf)
        sum *= scale;
        acc *= scale;
        m = newm;
        float ex = ok ? __expf(a - m) : 0.f;
        float cs = ex;
        #pragma unroll
        for (int o = 1; o < 64; o <<= 1) cs += __shfl_xor(cs, o);
        sum += cs;
        int lim = end - base; if (lim > 64) lim = 64;
        for (int i = 0; i < lim; ++i) {
            float w = __shfl(ex, i);
            int si = __shfl(s, i);
            acc += w * hs[si * H_DIM + lane];
        }
    }
    float val = acc / (sum + 1e-16f) + gbias[layer * H_DIM + lane];
    hout[wid * H_DIM + lane] = val > 0.f ? val : 0.f;
}

// ---------------- pooling: partial sums, 32 blocks per graph ----------------
__global__ __launch_bounds__(256) void k_pool(const float* __restrict__ h,
                                              float* __restrict__ gsum) {
    int g = blockIdx.x / POOL_CHUNKS;
    int chunk = blockIdx.x % POOL_CHUNKS;
    int wave = threadIdx.x >> 6, lane = threadIdx.x & 63;
    const int per_chunk = (NODES_PER_GRAPH + POOL_CHUNKS - 1) / POOL_CHUNKS; // 63
    int n0 = g * NODES_PER_GRAPH + chunk * per_chunk;
    int n1 = g * NODES_PER_GRAPH + min((chunk + 1) * per_chunk, NODES_PER_GRAPH);
    float sum = 0.f;
    for (int n = n0 + wave; n < n1; n += 4)
        sum += h[(size_t)n * H_DIM + lane];
    __shared__ float spart[4][64];
    spart[wave][lane] = sum;
    __syncthreads();
    if (wave == 0) {
        float tot = spart[0][lane] + spart[1][lane] + spart[2][lane] + spart[3][lane];
        atomicAdd(gsum + g * H_DIM + lane, tot);
    }
}

// ---------------- head MLP: one wave per graph ----------------
__global__ __launch_bounds__(64) void k_head2(const float* __restrict__ gsum,
                                              const float* __restrict__ gf,
                                              const float* __restrict__ Wg,
                                              const float* __restrict__ bg,
                                              const float* __restrict__ Wc,
                                              const float* __restrict__ bc,
                                              const float* __restrict__ Wo,
                                              const float* __restrict__ bo,
                                              float* __restrict__ out) {
    int g = blockIdx.x;
    int lane = threadIdx.x;
    __shared__ float sgraph[64];
    __shared__ float sgf[64];
    sgraph[lane] = gsum[g * H_DIM + lane] / (float)NODES_PER_GRAPH;
    float gv = bg[lane];
    #pragma unroll
    for (int k = 0; k < 6; ++k) gv += gf[g * 6 + k] * Wg[k * 64 + lane];
    sgf[lane] = gv;
    __syncthreads();
    float cj = bc[lane];
    #pragma unroll
    for (int k = 0; k < 64; ++k) cj += sgraph[k] * Wc[k * 64 + lane];
    #pragma unroll
    for (int k = 0; k < 64; ++k) cj += sgf[k] * Wc[(64 + k) * 64 + lane];
    cj = cj > 0.f ? cj : 0.f;
    float o = cj * Wo[lane];
    #pragma unroll
    for (int m = 1; m < 64; m <<= 1) o += __shfl_xor(o, m);
    if (lane == 0) out[g] = o + bo[0];
}

extern "C" void kernel_launch(void* const* d_in, const int* in_sizes, int n_in,
                              void* d_out, int out_size, void* d_ws, size_t ws_size,
                              hipStream_t stream) {
    const float* x        = (const float*)d_in[0];
    const float* ea       = (const float*)d_in[1];
    const float* gf       = (const float*)d_in[2];
    const int*   ei       = (const int*)d_in[3];
    const float* W_embed  = (const float*)d_in[5];
    const float* b_embed  = (const float*)d_in[6];
    const float* W_glob   = (const float*)d_in[7];
    const float* b_glob   = (const float*)d_in[8];
    const float* lin_W    = (const float*)d_in[9];
    const float* att_src  = (const float*)d_in[10];
    const float* att_dst  = (const float*)d_in[11];
    const float* lin_eW   = (const float*)d_in[12];
    const float* att_edge = (const float*)d_in[13];
    const float* gat_bias = (const float*)d_in[14];
    const float* W_comb   = (const float*)d_in[15];
    const float* b_comb   = (const float*)d_in[16];
    const float* W_out    = (const float*)d_in[17];
    const float* b_out    = (const float*)d_in[18];
    float* out = (float*)d_out;
    float* ws  = (float*)d_ws;

    float* h      = ws + OFF_H;
    float* hs     = ws + OFF_HS;
    float* asrc   = ws + OFF_ASRC;
    float* adst   = ws + OFF_ADST;
    float* cbuf   = ws + OFF_CBUF;
    int*   cnt    = (int*)(ws + OFF_CNT);
    float* gsum   = ws + OFF_GSUM;
    int*   rowp   = (int*)(ws + OFF_ROWP);
    int*   cur    = (int*)(ws + OFF_CUR);
    int*   bsum   = (int*)(ws + OFF_BSUM);
    int*   s_srt  = (int*)(ws + OFF_SSRT);
    float* ea_srt = ws + OFF_EASRT;

    const int egrid = (N_EDGES + 255) / 256;

    hipMemsetAsync(ws + OFF_ZERO, 0, (size_t)(OFF_ZEND - OFF_ZERO) * sizeof(float), stream);
    k_embed<<<2560, 256, 0, stream>>>(x, W_embed, b_embed, h);
    k_edgecoef<<<1, 128, 0, stream>>>(lin_eW, att_edge, cbuf);

    // CSR by dst
    k_hist<<<egrid, 256, 0, stream>>>(ei, cnt);
    k_scan1<<<NB_SCAN, 256, 0, stream>>>(cnt, rowp, bsum);
    k_scan2<<<1, 256, 0, stream>>>(bsum);
    k_scan3<<<NB_SCAN, 256, 0, stream>>>(rowp, bsum, cur);
    k_fill<<<egrid, 256, 0, stream>>>(ei, ea, cur, s_srt, ea_srt);

    for (int l = 0; l < 2; ++l) {
        k_hs<<<2560, 256, 0, stream>>>(h, lin_W + l * 64 * 64,
                                       att_src + l * 64, att_dst + l * 64,
                                       hs, asrc, adst);
        k_fused<<<(N_NODES + 3) / 4, 256, 0, stream>>>(rowp, s_srt, ea_srt,
                                                       asrc, adst, hs, cbuf, l,
                                                       gat_bias, h);
    }

    k_pool<<<N_GRAPH * POOL_CHUNKS, 256, 0, stream>>>(h, gsum);
    k_head2<<<N_GRAPH, 64, 0, stream>>>(gsum, gf, W_glob, b_glob,
                                        W_comb, b_comb, W_out, b_out, out);
}

// Round 4
// 315.804 us; speedup vs baseline: 3.2049x; 1.3400x over previous
//
#include <hip/hip_runtime.h>
#include <math.h>

#define N_NODES 50000
#define N_EDGES 1200000
#define N_GRAPH 25
#define F_IN 128
#define H_DIM 64
#define NODES_PER_GRAPH 2000
#define POOL_CHUNKS 32

#define NBUCK 196          // ceil(N/256) coarse buckets (d >> 8)
#define BUCK_CAP 8000      // mean 6122, +24 sigma
#define EPB 4096           // edges per block in k_bin
#define NB_BIN ((N_EDGES + EPB - 1) / EPB)   // 293

// ---------------- workspace layout (4B units) ----------------
#define OFF_H     0                         // N*64 f
#define OFF_HS    (N_NODES*64)              // N*64 f  (aliased as bin-stage during CSR build)
#define OFF_ASRC  (OFF_HS + N_NODES*64)     // N f
#define OFF_ADST  (OFF_ASRC + N_NODES)      // N f
#define OFF_CBUF  (OFF_ADST + N_NODES)      // 16 f
#define OFF_ZERO  (OFF_CBUF + 16)           // zeroed region start
#define OFF_BCUR  OFF_ZERO                  // 256 i (196 used)
#define OFF_GSUM  (OFF_BCUR + 256)          // G*64 f
#define OFF_ZEND  (OFF_GSUM + N_GRAPH*64)
#define OFF_BBASE OFF_ZEND                  // 256 i
#define OFF_ROWP  (OFF_BBASE + 256)         // N+2 i
#define OFF_ESRT  (OFF_ROWP + N_NODES + 2)  // E uint2 (8B aligned: offset is even)

// ---------------- embed: h = x @ W_embed + b ----------------
__global__ __launch_bounds__(256) void k_embed(const float* __restrict__ x,
                                               const float* __restrict__ W,
                                               const float* __restrict__ b,
                                               float* __restrict__ h) {
    __shared__ float sW[F_IN * H_DIM];
    __shared__ float sx[4][F_IN];
    for (int i = threadIdx.x; i < F_IN * H_DIM; i += 256) sW[i] = W[i];
    int wave = threadIdx.x >> 6, lane = threadIdx.x & 63;
    float bj = b[lane];
    __syncthreads();
    for (int n0 = blockIdx.x * 4; n0 < N_NODES; n0 += gridDim.x * 4) {
        int n = n0 + wave;
        __syncthreads();
        if (n < N_NODES) {
            sx[wave][lane]      = x[n * F_IN + lane];
            sx[wave][lane + 64] = x[n * F_IN + 64 + lane];
        }
        __syncthreads();
        if (n < N_NODES) {
            float acc = bj;
            #pragma unroll
            for (int k = 0; k < F_IN; ++k) acc += sx[wave][k] * sW[k * H_DIM + lane];
            h[n * H_DIM + lane] = acc;
        }
    }
}

// ---------------- hs = hin @ linW (+ attn scalars) ----------------
__global__ __launch_bounds__(256) void k_hs(const float* __restrict__ hin,
                                            const float* __restrict__ W,
                                            const float* __restrict__ attS,
                                            const float* __restrict__ attD,
                                            float* __restrict__ hs,
                                            float* __restrict__ asrc,
                                            float* __restrict__ adst) {
    __shared__ float sW[H_DIM * H_DIM];
    __shared__ float sx[4][H_DIM];
    for (int i = threadIdx.x; i < H_DIM * H_DIM; i += 256) sW[i] = W[i];
    int wave = threadIdx.x >> 6, lane = threadIdx.x & 63;
    float aS = attS[lane], aD = attD[lane];
    __syncthreads();
    for (int n0 = blockIdx.x * 4; n0 < N_NODES; n0 += gridDim.x * 4) {
        int n = n0 + wave;
        __syncthreads();
        if (n < N_NODES) sx[wave][lane] = hin[n * H_DIM + lane];
        __syncthreads();
        if (n < N_NODES) {
            float acc = 0.f;
            #pragma unroll
            for (int k = 0; k < H_DIM; ++k) acc += sx[wave][k] * sW[k * H_DIM + lane];
            hs[n * H_DIM + lane] = acc;
            float rs = acc * aS, rd = acc * aD;
            #pragma unroll
            for (int m = 1; m < 64; m <<= 1) {
                rs += __shfl_xor(rs, m);
                rd += __shfl_xor(rd, m);
            }
            if (lane == 0) { asrc[n] = rs; adst[n] = rd; }
        }
    }
}

// ---------------- per-layer edge coefficient ----------------
__global__ void k_edgecoef(const float* __restrict__ linE,
                           const float* __restrict__ attE,
                           float* __restrict__ cbuf) {
    int l = threadIdx.x >> 6, j = threadIdx.x & 63;
    float v = linE[l * 64 + j] * attE[l * 64 + j];
    #pragma unroll
    for (int m = 1; m < 64; m <<= 1) v += __shfl_xor(v, m);
    if (j == 0) cbuf[l] = v;
}

// ---------------- shared block scan helper ----------------
__device__ __forceinline__ int block_excl_scan(int v, int tid, int* lds, int* total) {
    int lane = tid & 63, w = tid >> 6;
    int incl = v;
    #pragma unroll
    for (int off = 1; off < 64; off <<= 1) {
        int t = __shfl_up(incl, off);
        if (lane >= off) incl += t;
    }
    if (lane == 63) lds[w] = incl;
    __syncthreads();
    int wo = 0;
    for (int i = 0; i < w; ++i) wo += lds[i];
    *total = lds[0] + lds[1] + lds[2] + lds[3];
    __syncthreads();
    return wo + incl - v;
}

// ---------------- pass 1: bin edges into coarse buckets (packed 8B) ----------------
__global__ __launch_bounds__(256) void k_bin(const int* __restrict__ ei,
                                             const float* __restrict__ ea,
                                             uint2* __restrict__ stage,
                                             int* __restrict__ bcur) {
    __shared__ int lcnt[NBUCK];
    __shared__ int lbase[NBUCK];
    int tid = threadIdx.x;
    for (int i = tid; i < NBUCK; i += 256) lcnt[i] = 0;
    __syncthreads();
    int e0 = blockIdx.x * EPB;
    unsigned pw0[16], pw1[16];
    #pragma unroll
    for (int k = 0; k < 16; ++k) {
        int e = e0 + k * 256 + tid;
        bool ok = e < N_EDGES;
        int s = ok ? ei[e] : 0;
        int d = ok ? ei[N_EDGES + e] : 0;
        float v = ok ? ea[e] : 0.f;
        pw0[k] = (unsigned)s | ((unsigned)d << 16);
        pw1[k] = __float_as_uint(v);
        if (ok) atomicAdd(&lcnt[d >> 8], 1);
    }
    __syncthreads();
    for (int i = tid; i < NBUCK; i += 256) {
        lbase[i] = atomicAdd(&bcur[i], lcnt[i]);
        lcnt[i] = 0;
    }
    __syncthreads();
    #pragma unroll
    for (int k = 0; k < 16; ++k) {
        int e = e0 + k * 256 + tid;
        if (e < N_EDGES) {
            int b = pw0[k] >> 24;                 // = d >> 8
            int pos = lbase[b] + atomicAdd(&lcnt[b], 1);
            uint2 t; t.x = pw0[k]; t.y = pw1[k];
            stage[b * BUCK_CAP + pos] = t;
        }
    }
}

// ---------------- bucket base scan (1 block) ----------------
__global__ __launch_bounds__(256) void k_bscan(const int* __restrict__ bcur,
                                               int* __restrict__ bbase,
                                               int* __restrict__ rowp) {
    __shared__ int lds[4];
    int v = (threadIdx.x < NBUCK) ? bcur[threadIdx.x] : 0;
    int total;
    int ex = block_excl_scan(v, threadIdx.x, lds, &total);
    if (threadIdx.x < NBUCK) bbase[threadIdx.x] = ex;
    if (threadIdx.x == 0) rowp[N_NODES] = N_EDGES;
}

// ---------------- pass 2: per-bucket hist + scan + scatter (cache-resident) --------
__global__ __launch_bounds__(256) void k_group(const uint2* __restrict__ stage,
                                               const int* __restrict__ bcur,
                                               const int* __restrict__ bbase,
                                               int* __restrict__ rowp,
                                               uint2* __restrict__ esrt) {
    int b = blockIdx.x;
    int tid = threadIdx.x;
    int cntb = bcur[b];
    int base = bbase[b];
    __shared__ int lcnt[256];
    __shared__ int lofs[256];
    __shared__ int slds[4];
    lcnt[tid] = 0;
    __syncthreads();
    const uint2* reg = stage + b * BUCK_CAP;
    for (int i = tid; i < cntb; i += 256)
        atomicAdd(&lcnt[(reg[i].x >> 16) & 255], 1);
    __syncthreads();
    int total;
    int ex = block_excl_scan(lcnt[tid], tid, slds, &total);
    lofs[tid] = base + ex;
    int n = b * 256 + tid;
    if (n < N_NODES) rowp[n] = base + ex;
    __syncthreads();
    lcnt[tid] = 0;
    __syncthreads();
    for (int i = tid; i < cntb; i += 256) {
        uint2 v = reg[i];
        int dloc = (v.x >> 16) & 255;
        int pos = lofs[dloc] + atomicAdd(&lcnt[dloc], 1);
        esrt[pos] = v;
    }
}

// ---------------- fused GAT layer: per-dst online softmax + message accum ----------
__global__ __launch_bounds__(256) void k_fused(const int* __restrict__ rowp,
                                               const uint2* __restrict__ esrt,
                                               const float* __restrict__ asrc,
                                               const float* __restrict__ adst,
                                               const float* __restrict__ hs,
                                               const float* __restrict__ cbuf,
                                               int layer,
                                               const float* __restrict__ gbias,
                                               float* __restrict__ hout) {
    int wid = (blockIdx.x * 256 + threadIdx.x) >> 6;
    int lane = threadIdx.x & 63;
    if (wid >= N_NODES) return;
    int beg = rowp[wid], end = rowp[wid + 1];
    float adv = adst[wid];
    float c = cbuf[layer];
    float m = -INFINITY, sum = 0.f, acc = 0.f;

    for (int base = beg; base < end; base += 64) {
        int idx = base + lane;
        bool ok = idx < end;
        uint2 v; v.x = 0; v.y = 0;
        if (ok) v = esrt[idx];
        int s = v.x & 0xFFFF;
        float a;
        if (ok) {
            a = asrc[s] + adv + c * __uint_as_float(v.y);
            a = a >= 0.f ? a : 0.2f * a;
        } else {
            a = -INFINITY;
        }
        float cm = a;
        #pragma unroll
        for (int o = 1; o < 64; o <<= 1) cm = fmaxf(cm, __shfl_xor(cm, o));
        float newm = fmaxf(m, cm);
        float scale = __expf(m - newm);   // 0 on first chunk (m=-inf)
        sum *= scale;
        acc *= scale;
        m = newm;
        float ex = ok ? __expf(a - m) : 0.f;
        float cs = ex;
        #pragma unroll
        for (int o = 1; o < 64; o <<= 1) cs += __shfl_xor(cs, o);
        sum += cs;
        int lim = end - base; if (lim > 64) lim = 64;
        for (int i = 0; i < lim; ++i) {
            float w = __shfl(ex, i);
            int si = __shfl(s, i);
            acc += w * hs[si * H_DIM + lane];
        }
    }
    float val = acc / (sum + 1e-16f) + gbias[layer * H_DIM + lane];
    hout[wid * H_DIM + lane] = val > 0.f ? val : 0.f;
}

// ---------------- pooling: partial sums, 32 blocks per graph ----------------
__global__ __launch_bounds__(256) void k_pool(const float* __restrict__ h,
                                              float* __restrict__ gsum) {
    int g = blockIdx.x / POOL_CHUNKS;
    int chunk = blockIdx.x % POOL_CHUNKS;
    int wave = threadIdx.x >> 6, lane = threadIdx.x & 63;
    const int per_chunk = (NODES_PER_GRAPH + POOL_CHUNKS - 1) / POOL_CHUNKS;
    int n0 = g * NODES_PER_GRAPH + chunk * per_chunk;
    int n1 = g * NODES_PER_GRAPH + min((chunk + 1) * per_chunk, NODES_PER_GRAPH);
    float sum = 0.f;
    for (int n = n0 + wave; n < n1; n += 4)
        sum += h[(size_t)n * H_DIM + lane];
    __shared__ float spart[4][64];
    spart[wave][lane] = sum;
    __syncthreads();
    if (wave == 0) {
        float tot = spart[0][lane] + spart[1][lane] + spart[2][lane] + spart[3][lane];
        atomicAdd(gsum + g * H_DIM + lane, tot);
    }
}

// ---------------- head MLP: one wave per graph ----------------
__global__ __launch_bounds__(64) void k_head2(const float* __restrict__ gsum,
                                              const float* __restrict__ gf,
                                              const float* __restrict__ Wg,
                                              const float* __restrict__ bg,
                                              const float* __restrict__ Wc,
                                              const float* __restrict__ bc,
                                              const float* __restrict__ Wo,
                                              const float* __restrict__ bo,
                                              float* __restrict__ out) {
    int g = blockIdx.x;
    int lane = threadIdx.x;
    __shared__ float sgraph[64];
    __shared__ float sgf[64];
    sgraph[lane] = gsum[g * H_DIM + lane] / (float)NODES_PER_GRAPH;
    float gv = bg[lane];
    #pragma unroll
    for (int k = 0; k < 6; ++k) gv += gf[g * 6 + k] * Wg[k * 64 + lane];
    sgf[lane] = gv;
    __syncthreads();
    float cj = bc[lane];
    #pragma unroll
    for (int k = 0; k < 64; ++k) cj += sgraph[k] * Wc[k * 64 + lane];
    #pragma unroll
    for (int k = 0; k < 64; ++k) cj += sgf[k] * Wc[(64 + k) * 64 + lane];
    cj = cj > 0.f ? cj : 0.f;
    float o = cj * Wo[lane];
    #pragma unroll
    for (int m = 1; m < 64; m <<= 1) o += __shfl_xor(o, m);
    if (lane == 0) out[g] = o + bo[0];
}

extern "C" void kernel_launch(void* const* d_in, const int* in_sizes, int n_in,
                              void* d_out, int out_size, void* d_ws, size_t ws_size,
                              hipStream_t stream) {
    const float* x        = (const float*)d_in[0];
    const float* ea       = (const float*)d_in[1];
    const float* gf       = (const float*)d_in[2];
    const int*   ei       = (const int*)d_in[3];
    const float* W_embed  = (const float*)d_in[5];
    const float* b_embed  = (const float*)d_in[6];
    const float* W_glob   = (const float*)d_in[7];
    const float* b_glob   = (const float*)d_in[8];
    const float* lin_W    = (const float*)d_in[9];
    const float* att_src  = (const float*)d_in[10];
    const float* att_dst  = (const float*)d_in[11];
    const float* lin_eW   = (const float*)d_in[12];
    const float* att_edge = (const float*)d_in[13];
    const float* gat_bias = (const float*)d_in[14];
    const float* W_comb   = (const float*)d_in[15];
    const float* b_comb   = (const float*)d_in[16];
    const float* W_out    = (const float*)d_in[17];
    const float* b_out    = (const float*)d_in[18];
    float* out = (float*)d_out;
    float* ws  = (float*)d_ws;

    float* h      = ws + OFF_H;
    float* hs     = ws + OFF_HS;
    uint2* stage  = (uint2*)(ws + OFF_HS);   // aliased: used before hs is written
    float* asrc   = ws + OFF_ASRC;
    float* adst   = ws + OFF_ADST;
    float* cbuf   = ws + OFF_CBUF;
    int*   bcur   = (int*)(ws + OFF_BCUR);
    float* gsum   = ws + OFF_GSUM;
    int*   bbase  = (int*)(ws + OFF_BBASE);
    int*   rowp   = (int*)(ws + OFF_ROWP);
    uint2* esrt   = (uint2*)(ws + OFF_ESRT);

    hipMemsetAsync(ws + OFF_ZERO, 0, (size_t)(OFF_ZEND - OFF_ZERO) * sizeof(float), stream);
    k_embed<<<2560, 256, 0, stream>>>(x, W_embed, b_embed, h);
    k_edgecoef<<<1, 128, 0, stream>>>(lin_eW, att_edge, cbuf);

    // CSR by dst: two-level binned counting sort (no global per-node atomics)
    k_bin<<<NB_BIN, 256, 0, stream>>>(ei, ea, stage, bcur);
    k_bscan<<<1, 256, 0, stream>>>(bcur, bbase, rowp);
    k_group<<<NBUCK, 256, 0, stream>>>(stage, bcur, bbase, rowp, esrt);

    for (int l = 0; l < 2; ++l) {
        k_hs<<<2560, 256, 0, stream>>>(h, lin_W + l * 64 * 64,
                                       att_src + l * 64, att_dst + l * 64,
                                       hs, asrc, adst);
        k_fused<<<(N_NODES + 3) / 4, 256, 0, stream>>>(rowp, esrt,
                                                       asrc, adst, hs, cbuf, l,
                                                       gat_bias, h);
    }

    k_pool<<<N_GRAPH * POOL_CHUNKS, 256, 0, stream>>>(h, gsum);
    k_head2<<<N_GRAPH, 64, 0, stream>>>(gsum, gf, W_glob, b_glob,
                                        W_comb, b_comb, W_out, b_out, out);
}

// Round 5
// 211.002 us; speedup vs baseline: 4.7967x; 1.4967x over previous
//
#include <hip/hip_runtime.h>
#include <math.h>

#define N_NODES 50000
#define N_EDGES 1200000
#define N_GRAPH 25
#define F_IN 128
#define H_DIM 64
#define NODES_PER_GRAPH 2000
#define POOL_CHUNKS 32

#define NBUCK 196          // ceil(N/256) coarse buckets (d >> 8)
#define BUCK_CAP 8000      // mean 6122, +24 sigma
#define EPB 4096           // edges per block in k_bin
#define NB_BIN ((N_EDGES + EPB - 1) / EPB)   // 293

// ---------------- workspace layout (4B units) ----------------
#define OFF_H     0                         // N*64 f
#define OFF_HS    (N_NODES*64)              // N*64 f  (aliased as bin-stage during CSR build)
#define OFF_ASRC  (OFF_HS + N_NODES*64)     // N f
#define OFF_ADST  (OFF_ASRC + N_NODES)      // N f
#define OFF_CBUF  (OFF_ADST + N_NODES)      // 16 f
#define OFF_ZERO  (OFF_CBUF + 16)           // zeroed region start
#define OFF_BCUR  OFF_ZERO                  // 256 i (196 used)
#define OFF_GSUM  (OFF_BCUR + 256)          // G*64 f
#define OFF_ZEND  (OFF_GSUM + N_GRAPH*64)
#define OFF_BBASE OFF_ZEND                  // 256 i
#define OFF_ROWP  (OFF_BBASE + 256)         // N+2 i
#define OFF_ESRT  (OFF_ROWP + N_NODES + 2)  // E uint2 (8B aligned)

// ---------------- embed: h = x @ W_embed + b  (scalar-operand GEMV) ----------------
__global__ __launch_bounds__(256) void k_embed(const float* __restrict__ x,
                                               const float* __restrict__ W,
                                               const float* __restrict__ b,
                                               float* __restrict__ h) {
    int lane = threadIdx.x & 63;
    int wid0 = (blockIdx.x * 256 + threadIdx.x) >> 6;
    int nw = gridDim.x * 4;
    float wc[F_IN];
    #pragma unroll
    for (int k = 0; k < F_IN; ++k) wc[k] = W[k * H_DIM + lane];
    float bj = b[lane];
    for (int n = wid0; n < N_NODES; n += nw) {
        int nu = __builtin_amdgcn_readfirstlane(n);
        const float* row = x + (size_t)nu * F_IN;
        float acc = bj;
        #pragma unroll
        for (int k = 0; k < F_IN; ++k) acc += row[k] * wc[k];
        h[nu * H_DIM + lane] = acc;
    }
}

// ---------------- hs = hin @ linW (+ attn scalars), scalar-operand GEMV ------------
__global__ __launch_bounds__(256) void k_hs(const float* __restrict__ hin,
                                            const float* __restrict__ W,
                                            const float* __restrict__ attS,
                                            const float* __restrict__ attD,
                                            float* __restrict__ hs,
                                            float* __restrict__ asrc,
                                            float* __restrict__ adst) {
    int lane = threadIdx.x & 63;
    int wid0 = (blockIdx.x * 256 + threadIdx.x) >> 6;
    int nw = gridDim.x * 4;
    float wc[H_DIM];
    #pragma unroll
    for (int k = 0; k < H_DIM; ++k) wc[k] = W[k * H_DIM + lane];
    float aS = attS[lane], aD = attD[lane];
    for (int n = wid0; n < N_NODES; n += nw) {
        int nu = __builtin_amdgcn_readfirstlane(n);
        const float* row = hin + (size_t)nu * H_DIM;
        float acc = 0.f;
        #pragma unroll
        for (int k = 0; k < H_DIM; ++k) acc += row[k] * wc[k];
        hs[nu * H_DIM + lane] = acc;
        float rs = acc * aS, rd = acc * aD;
        #pragma unroll
        for (int m = 1; m < 64; m <<= 1) {
            rs += __shfl_xor(rs, m);
            rd += __shfl_xor(rd, m);
        }
        if (lane == 0) { asrc[nu] = rs; adst[nu] = rd; }
    }
}

// ---------------- per-layer edge coefficient ----------------
__global__ void k_edgecoef(const float* __restrict__ linE,
                           const float* __restrict__ attE,
                           float* __restrict__ cbuf) {
    int l = threadIdx.x >> 6, j = threadIdx.x & 63;
    float v = linE[l * 64 + j] * attE[l * 64 + j];
    #pragma unroll
    for (int m = 1; m < 64; m <<= 1) v += __shfl_xor(v, m);
    if (j == 0) cbuf[l] = v;
}

// ---------------- shared block scan helper ----------------
__device__ __forceinline__ int block_excl_scan(int v, int tid, int* lds, int* total) {
    int lane = tid & 63, w = tid >> 6;
    int incl = v;
    #pragma unroll
    for (int off = 1; off < 64; off <<= 1) {
        int t = __shfl_up(incl, off);
        if (lane >= off) incl += t;
    }
    if (lane == 63) lds[w] = incl;
    __syncthreads();
    int wo = 0;
    for (int i = 0; i < w; ++i) wo += lds[i];
    *total = lds[0] + lds[1] + lds[2] + lds[3];
    __syncthreads();
    return wo + incl - v;
}

// ---------------- pass 1: bin edges into coarse buckets (packed 8B) ----------------
__global__ __launch_bounds__(256) void k_bin(const int* __restrict__ ei,
                                             const float* __restrict__ ea,
                                             uint2* __restrict__ stage,
                                             int* __restrict__ bcur) {
    __shared__ int lcnt[NBUCK];
    __shared__ int lbase[NBUCK];
    int tid = threadIdx.x;
    for (int i = tid; i < NBUCK; i += 256) lcnt[i] = 0;
    __syncthreads();
    int e0 = blockIdx.x * EPB;
    unsigned pw0[16], pw1[16];
    #pragma unroll
    for (int k = 0; k < 16; ++k) {
        int e = e0 + k * 256 + tid;
        bool ok = e < N_EDGES;
        int s = ok ? ei[e] : 0;
        int d = ok ? ei[N_EDGES + e] : 0;
        float v = ok ? ea[e] : 0.f;
        pw0[k] = (unsigned)s | ((unsigned)d << 16);
        pw1[k] = __float_as_uint(v);
        if (ok) atomicAdd(&lcnt[d >> 8], 1);
    }
    __syncthreads();
    for (int i = tid; i < NBUCK; i += 256) {
        lbase[i] = atomicAdd(&bcur[i], lcnt[i]);
        lcnt[i] = 0;
    }
    __syncthreads();
    #pragma unroll
    for (int k = 0; k < 16; ++k) {
        int e = e0 + k * 256 + tid;
        if (e < N_EDGES) {
            int b = pw0[k] >> 24;                 // = d >> 8
            int pos = lbase[b] + atomicAdd(&lcnt[b], 1);
            uint2 t; t.x = pw0[k]; t.y = pw1[k];
            stage[b * BUCK_CAP + pos] = t;
        }
    }
}

// ---------------- bucket base scan (1 block) ----------------
__global__ __launch_bounds__(256) void k_bscan(const int* __restrict__ bcur,
                                               int* __restrict__ bbase,
                                               int* __restrict__ rowp) {
    __shared__ int lds[4];
    int v = (threadIdx.x < NBUCK) ? bcur[threadIdx.x] : 0;
    int total;
    int ex = block_excl_scan(v, threadIdx.x, lds, &total);
    if (threadIdx.x < NBUCK) bbase[threadIdx.x] = ex;
    if (threadIdx.x == 0) rowp[N_NODES] = N_EDGES;
}

// ---------------- pass 2: per-bucket hist + scan + scatter ----------------
__global__ __launch_bounds__(256) void k_group(const uint2* __restrict__ stage,
                                               const int* __restrict__ bcur,
                                               const int* __restrict__ bbase,
                                               int* __restrict__ rowp,
                                               uint2* __restrict__ esrt) {
    int b = blockIdx.x;
    int tid = threadIdx.x;
    int cntb = bcur[b];
    int base = bbase[b];
    __shared__ int lcnt[256];
    __shared__ int lofs[256];
    __shared__ int slds[4];
    lcnt[tid] = 0;
    __syncthreads();
    const uint2* reg = stage + b * BUCK_CAP;
    for (int i = tid; i < cntb; i += 256)
        atomicAdd(&lcnt[(reg[i].x >> 16) & 255], 1);
    __syncthreads();
    int total;
    int ex = block_excl_scan(lcnt[tid], tid, slds, &total);
    lofs[tid] = base + ex;
    int n = b * 256 + tid;
    if (n < N_NODES) rowp[n] = base + ex;
    __syncthreads();
    lcnt[tid] = 0;
    __syncthreads();
    for (int i = tid; i < cntb; i += 256) {
        uint2 v = reg[i];
        int dloc = (v.x >> 16) & 255;
        int pos = lofs[dloc] + atomicAdd(&lcnt[dloc], 1);
        esrt[pos] = v;
    }
}

// ---------------- fused GAT layer: online softmax + grouped float4 messages --------
__global__ __launch_bounds__(256) void k_fused(const int* __restrict__ rowp,
                                               const uint2* __restrict__ esrt,
                                               const float* __restrict__ asrc,
                                               const float* __restrict__ adst,
                                               const float* __restrict__ hs,
                                               const float* __restrict__ cbuf,
                                               int layer,
                                               const float* __restrict__ gbias,
                                               float* __restrict__ hout) {
    int wid = (blockIdx.x * 256 + threadIdx.x) >> 6;
    int lane = threadIdx.x & 63;
    if (wid >= N_NODES) return;
    int beg = rowp[wid], end = rowp[wid + 1];
    float adv = adst[wid];
    float c = cbuf[layer];
    float m = -INFINITY, sum = 0.f;
    float4 acc = make_float4(0.f, 0.f, 0.f, 0.f);
    int g = lane >> 4, fl = lane & 15;
    const float4* hs4 = (const float4*)hs;

    for (int base = beg; base < end; base += 64) {
        int idx = base + lane;
        bool ok = idx < end;
        uint2 v; v.x = 0; v.y = 0;
        if (ok) v = esrt[idx];
        int s = v.x & 0xFFFF;
        float a;
        if (ok) {
            a = asrc[s] + adv + c * __uint_as_float(v.y);
            a = a >= 0.f ? a : 0.2f * a;
        } else {
            a = -INFINITY;
        }
        float cm = a;
        #pragma unroll
        for (int o = 1; o < 64; o <<= 1) cm = fmaxf(cm, __shfl_xor(cm, o));
        float newm = fmaxf(m, cm);
        float scale = __expf(m - newm);   // 0 on first chunk (m=-inf)
        sum *= scale;
        acc.x *= scale; acc.y *= scale; acc.z *= scale; acc.w *= scale;
        m = newm;
        float ex = ok ? __expf(a - m) : 0.f;
        float cs = ex;
        #pragma unroll
        for (int o = 1; o < 64; o <<= 1) cs += __shfl_xor(cs, o);
        sum += cs;

        int lim = end - base; if (lim > 64) lim = 64;
        // message accumulation: 4 groups of 16 lanes, one edge per group,
        // float4 per lane; 2-deep unroll -> 8 independent gathers in flight.
        int t = g;
        for (; t + 4 < lim; t += 8) {
            float w0 = __shfl(ex, t),     w1 = __shfl(ex, t + 4);
            int   s0 = __shfl(s, t),      s1 = __shfl(s, t + 4);
            float4 r0 = hs4[s0 * 16 + fl];
            float4 r1 = hs4[s1 * 16 + fl];
            acc.x += w0 * r0.x; acc.y += w0 * r0.y; acc.z += w0 * r0.z; acc.w += w0 * r0.w;
            acc.x += w1 * r1.x; acc.y += w1 * r1.y; acc.z += w1 * r1.z; acc.w += w1 * r1.w;
        }
        for (; t < lim; t += 4) {
            float w0 = __shfl(ex, t);
            int   s0 = __shfl(s, t);
            float4 r0 = hs4[s0 * 16 + fl];
            acc.x += w0 * r0.x; acc.y += w0 * r0.y; acc.z += w0 * r0.z; acc.w += w0 * r0.w;
        }
    }
    // reduce the 4 group accumulators
    acc.x += __shfl_xor(acc.x, 16); acc.y += __shfl_xor(acc.y, 16);
    acc.z += __shfl_xor(acc.z, 16); acc.w += __shfl_xor(acc.w, 16);
    acc.x += __shfl_xor(acc.x, 32); acc.y += __shfl_xor(acc.y, 32);
    acc.z += __shfl_xor(acc.z, 32); acc.w += __shfl_xor(acc.w, 32);

    if (lane < 16) {
        float inv = 1.f / (sum + 1e-16f);
        float4 gb = ((const float4*)(gbias + layer * H_DIM))[lane];
        float4 val;
        val.x = acc.x * inv + gb.x; val.x = val.x > 0.f ? val.x : 0.f;
        val.y = acc.y * inv + gb.y; val.y = val.y > 0.f ? val.y : 0.f;
        val.z = acc.z * inv + gb.z; val.z = val.z > 0.f ? val.z : 0.f;
        val.w = acc.w * inv + gb.w; val.w = val.w > 0.f ? val.w : 0.f;
        ((float4*)(hout + (size_t)wid * H_DIM))[lane] = val;
    }
}

// ---------------- pooling: partial sums, 32 blocks per graph ----------------
__global__ __launch_bounds__(256) void k_pool(const float* __restrict__ h,
                                              float* __restrict__ gsum) {
    int g = blockIdx.x / POOL_CHUNKS;
    int chunk = blockIdx.x % POOL_CHUNKS;
    int wave = threadIdx.x >> 6, lane = threadIdx.x & 63;
    const int per_chunk = (NODES_PER_GRAPH + POOL_CHUNKS - 1) / POOL_CHUNKS;
    int n0 = g * NODES_PER_GRAPH + chunk * per_chunk;
    int n1 = g * NODES_PER_GRAPH + min((chunk + 1) * per_chunk, NODES_PER_GRAPH);
    float sum = 0.f;
    for (int n = n0 + wave; n < n1; n += 4)
        sum += h[(size_t)n * H_DIM + lane];
    __shared__ float spart[4][64];
    spart[wave][lane] = sum;
    __syncthreads();
    if (wave == 0) {
        float tot = spart[0][lane] + spart[1][lane] + spart[2][lane] + spart[3][lane];
        atomicAdd(gsum + g * H_DIM + lane, tot);
    }
}

// ---------------- head MLP: one wave per graph ----------------
__global__ __launch_bounds__(64) void k_head2(const float* __restrict__ gsum,
                                              const float* __restrict__ gf,
                                              const float* __restrict__ Wg,
                                              const float* __restrict__ bg,
                                              const float* __restrict__ Wc,
                                              const float* __restrict__ bc,
                                              const float* __restrict__ Wo,
                                              const float* __restrict__ bo,
                                              float* __restrict__ out) {
    int g = blockIdx.x;
    int lane = threadIdx.x;
    __shared__ float sgraph[64];
    __shared__ float sgf[64];
    sgraph[lane] = gsum[g * H_DIM + lane] / (float)NODES_PER_GRAPH;
    float gv = bg[lane];
    #pragma unroll
    for (int k = 0; k < 6; ++k) gv += gf[g * 6 + k] * Wg[k * 64 + lane];
    sgf[lane] = gv;
    __syncthreads();
    float cj = bc[lane];
    #pragma unroll
    for (int k = 0; k < 64; ++k) cj += sgraph[k] * Wc[k * 64 + lane];
    #pragma unroll
    for (int k = 0; k < 64; ++k) cj += sgf[k] * Wc[(64 + k) * 64 + lane];
    cj = cj > 0.f ? cj : 0.f;
    float o = cj * Wo[lane];
    #pragma unroll
    for (int m = 1; m < 64; m <<= 1) o += __shfl_xor(o, m);
    if (lane == 0) out[g] = o + bo[0];
}

extern "C" void kernel_launch(void* const* d_in, const int* in_sizes, int n_in,
                              void* d_out, int out_size, void* d_ws, size_t ws_size,
                              hipStream_t stream) {
    const float* x        = (const float*)d_in[0];
    const float* ea       = (const float*)d_in[1];
    const float* gf       = (const float*)d_in[2];
    const int*   ei       = (const int*)d_in[3];
    const float* W_embed  = (const float*)d_in[5];
    const float* b_embed  = (const float*)d_in[6];
    const float* W_glob   = (const float*)d_in[7];
    const float* b_glob   = (const float*)d_in[8];
    const float* lin_W    = (const float*)d_in[9];
    const float* att_src  = (const float*)d_in[10];
    const float* att_dst  = (const float*)d_in[11];
    const float* lin_eW   = (const float*)d_in[12];
    const float* att_edge = (const float*)d_in[13];
    const float* gat_bias = (const float*)d_in[14];
    const float* W_comb   = (const float*)d_in[15];
    const float* b_comb   = (const float*)d_in[16];
    const float* W_out    = (const float*)d_in[17];
    const float* b_out    = (const float*)d_in[18];
    float* out = (float*)d_out;
    float* ws  = (float*)d_ws;

    float* h      = ws + OFF_H;
    float* hs     = ws + OFF_HS;
    uint2* stage  = (uint2*)(ws + OFF_HS);   // aliased: used before hs is written
    float* asrc   = ws + OFF_ASRC;
    float* adst   = ws + OFF_ADST;
    float* cbuf   = ws + OFF_CBUF;
    int*   bcur   = (int*)(ws + OFF_BCUR);
    float* gsum   = ws + OFF_GSUM;
    int*   bbase  = (int*)(ws + OFF_BBASE);
    int*   rowp   = (int*)(ws + OFF_ROWP);
    uint2* esrt   = (uint2*)(ws + OFF_ESRT);

    hipMemsetAsync(ws + OFF_ZERO, 0, (size_t)(OFF_ZEND - OFF_ZERO) * sizeof(float), stream);
    k_embed<<<2560, 256, 0, stream>>>(x, W_embed, b_embed, h);
    k_edgecoef<<<1, 128, 0, stream>>>(lin_eW, att_edge, cbuf);

    // CSR by dst: two-level binned counting sort (no global per-node atomics)
    k_bin<<<NB_BIN, 256, 0, stream>>>(ei, ea, stage, bcur);
    k_bscan<<<1, 256, 0, stream>>>(bcur, bbase, rowp);
    k_group<<<NBUCK, 256, 0, stream>>>(stage, bcur, bbase, rowp, esrt);

    for (int l = 0; l < 2; ++l) {
        k_hs<<<2560, 256, 0, stream>>>(h, lin_W + l * 64 * 64,
                                       att_src + l * 64, att_dst + l * 64,
                                       hs, asrc, adst);
        k_fused<<<(N_NODES + 3) / 4, 256, 0, stream>>>(rowp, esrt,
                                                       asrc, adst, hs, cbuf, l,
                                                       gat_bias, h);
    }

    k_pool<<<N_GRAPH * POOL_CHUNKS, 256, 0, stream>>>(h, gsum);
    k_head2<<<N_GRAPH, 64, 0, stream>>>(gsum, gf, W_glob, b_glob,
                                        W_comb, b_comb, W_out, b_out, out);
}

// Round 6
// 203.864 us; speedup vs baseline: 4.9646x; 1.0350x over previous
//
#include <hip/hip_runtime.h>
#include <math.h>

#define N_NODES 50000
#define N_EDGES 1200000
#define N_GRAPH 25
#define F_IN 128
#define H_DIM 64
#define NODES_PER_GRAPH 2000
#define POOL_CHUNKS 32

#define NBUCK 196          // ceil(N/256) coarse buckets (d >> 8)
#define BUCK_CAP 8000      // mean 6122, +24 sigma
#define EPB 4096           // edges per block in k_bin
#define NB_BIN ((N_EDGES + EPB - 1) / EPB)   // 293

// ---------------- workspace layout (4B units) ----------------
#define OFF_H     0                         // N*64 f
#define OFF_HS    (N_NODES*64)              // N*64 f  (aliased as bin-stage during CSR build)
#define OFF_ASRC  (OFF_HS + N_NODES*64)     // N f
#define OFF_ADST  (OFF_ASRC + N_NODES)      // N f
#define OFF_CBUF  (OFF_ADST + N_NODES)      // 16 f
#define OFF_ZERO  (OFF_CBUF + 16)           // zeroed region start
#define OFF_BCUR  OFF_ZERO                  // 256 i (196 used)
#define OFF_GSUM  (OFF_BCUR + 256)          // G*64 f
#define OFF_ZEND  (OFF_GSUM + N_GRAPH*64)
#define OFF_BBASE OFF_ZEND                  // 256 i
#define OFF_ROWP  (OFF_BBASE + 256)         // N+2 i
#define OFF_ESRT  (OFF_ROWP + N_NODES + 2)  // E u32: src | bf16(ea)<<16

// ---------------- embed: h = x @ W_embed + b  (scalar-operand GEMV) ----------------
__global__ __launch_bounds__(256) void k_embed(const float* __restrict__ x,
                                               const float* __restrict__ W,
                                               const float* __restrict__ b,
                                               float* __restrict__ h) {
    int lane = threadIdx.x & 63;
    int wid0 = (blockIdx.x * 256 + threadIdx.x) >> 6;
    int nw = gridDim.x * 4;
    float wc[F_IN];
    #pragma unroll
    for (int k = 0; k < F_IN; ++k) wc[k] = W[k * H_DIM + lane];
    float bj = b[lane];
    for (int n = wid0; n < N_NODES; n += nw) {
        int nu = __builtin_amdgcn_readfirstlane(n);
        const float* row = x + (size_t)nu * F_IN;
        float acc = bj;
        #pragma unroll
        for (int k = 0; k < F_IN; ++k) acc += row[k] * wc[k];
        h[nu * H_DIM + lane] = acc;
    }
}

// ---------------- hs = hin @ linW (+ attn scalars), scalar-operand GEMV ------------
__global__ __launch_bounds__(256) void k_hs(const float* __restrict__ hin,
                                            const float* __restrict__ W,
                                            const float* __restrict__ attS,
                                            const float* __restrict__ attD,
                                            float* __restrict__ hs,
                                            float* __restrict__ asrc,
                                            float* __restrict__ adst) {
    int lane = threadIdx.x & 63;
    int wid0 = (blockIdx.x * 256 + threadIdx.x) >> 6;
    int nw = gridDim.x * 4;
    float wc[H_DIM];
    #pragma unroll
    for (int k = 0; k < H_DIM; ++k) wc[k] = W[k * H_DIM + lane];
    float aS = attS[lane], aD = attD[lane];
    for (int n = wid0; n < N_NODES; n += nw) {
        int nu = __builtin_amdgcn_readfirstlane(n);
        const float* row = hin + (size_t)nu * H_DIM;
        float acc = 0.f;
        #pragma unroll
        for (int k = 0; k < H_DIM; ++k) acc += row[k] * wc[k];
        hs[nu * H_DIM + lane] = acc;
        float rs = acc * aS, rd = acc * aD;
        #pragma unroll
        for (int m = 1; m < 64; m <<= 1) {
            rs += __shfl_xor(rs, m);
            rd += __shfl_xor(rd, m);
        }
        if (lane == 0) { asrc[nu] = rs; adst[nu] = rd; }
    }
}

// ---------------- shared block scan helper ----------------
__device__ __forceinline__ int block_excl_scan(int v, int tid, int* lds, int* total) {
    int lane = tid & 63, w = tid >> 6;
    int incl = v;
    #pragma unroll
    for (int off = 1; off < 64; off <<= 1) {
        int t = __shfl_up(incl, off);
        if (lane >= off) incl += t;
    }
    if (lane == 63) lds[w] = incl;
    __syncthreads();
    int wo = 0;
    for (int i = 0; i < w; ++i) wo += lds[i];
    *total = lds[0] + lds[1] + lds[2] + lds[3];
    __syncthreads();
    return wo + incl - v;
}

// ---------------- pass 1: bin edges into coarse buckets (packed 8B) ----------------
__global__ __launch_bounds__(256) void k_bin(const int* __restrict__ ei,
                                             const float* __restrict__ ea,
                                             uint2* __restrict__ stage,
                                             int* __restrict__ bcur) {
    __shared__ int lcnt[NBUCK];
    __shared__ int lbase[NBUCK];
    int tid = threadIdx.x;
    for (int i = tid; i < NBUCK; i += 256) lcnt[i] = 0;
    __syncthreads();
    int e0 = blockIdx.x * EPB;
    unsigned pw0[16], pw1[16];
    #pragma unroll
    for (int k = 0; k < 16; ++k) {
        int e = e0 + k * 256 + tid;
        bool ok = e < N_EDGES;
        int s = ok ? ei[e] : 0;
        int d = ok ? ei[N_EDGES + e] : 0;
        float v = ok ? ea[e] : 0.f;
        pw0[k] = (unsigned)s | ((unsigned)d << 16);
        pw1[k] = __float_as_uint(v);
        if (ok) atomicAdd(&lcnt[d >> 8], 1);
    }
    __syncthreads();
    for (int i = tid; i < NBUCK; i += 256) {
        lbase[i] = atomicAdd(&bcur[i], lcnt[i]);
        lcnt[i] = 0;
    }
    __syncthreads();
    #pragma unroll
    for (int k = 0; k < 16; ++k) {
        int e = e0 + k * 256 + tid;
        if (e < N_EDGES) {
            int b = pw0[k] >> 24;                 // = d >> 8
            int pos = lbase[b] + atomicAdd(&lcnt[b], 1);
            uint2 t; t.x = pw0[k]; t.y = pw1[k];
            stage[b * BUCK_CAP + pos] = t;
        }
    }
}

// ---------------- bucket base scan (1 block) + edge coefficients ----------------
__global__ __launch_bounds__(256) void k_bscan(const int* __restrict__ bcur,
                                               int* __restrict__ bbase,
                                               int* __restrict__ rowp,
                                               const float* __restrict__ linE,
                                               const float* __restrict__ attE,
                                               float* __restrict__ cbuf) {
    __shared__ int lds[4];
    if (threadIdx.x < 128) {
        int l = threadIdx.x >> 6, j = threadIdx.x & 63;
        float v = linE[l * 64 + j] * attE[l * 64 + j];
        #pragma unroll
        for (int m = 1; m < 64; m <<= 1) v += __shfl_xor(v, m);
        if (j == 0) cbuf[l] = v;
    }
    int v = (threadIdx.x < NBUCK) ? bcur[threadIdx.x] : 0;
    int total;
    int ex = block_excl_scan(v, threadIdx.x, lds, &total);
    if (threadIdx.x < NBUCK) bbase[threadIdx.x] = ex;
    if (threadIdx.x == 0) rowp[N_NODES] = N_EDGES;
}

// ---------------- pass 2: per-bucket hist + scan + scatter (emit 4B records) -------
__global__ __launch_bounds__(256) void k_group(const uint2* __restrict__ stage,
                                               const int* __restrict__ bcur,
                                               const int* __restrict__ bbase,
                                               int* __restrict__ rowp,
                                               unsigned* __restrict__ esrt) {
    int b = blockIdx.x;
    int tid = threadIdx.x;
    int cntb = bcur[b];
    int base = bbase[b];
    __shared__ int lcnt[256];
    __shared__ int lofs[256];
    __shared__ int slds[4];
    lcnt[tid] = 0;
    __syncthreads();
    const uint2* reg = stage + b * BUCK_CAP;
    for (int i = tid; i < cntb; i += 256)
        atomicAdd(&lcnt[(reg[i].x >> 16) & 255], 1);
    __syncthreads();
    int total;
    int ex = block_excl_scan(lcnt[tid], tid, slds, &total);
    lofs[tid] = base + ex;
    int n = b * 256 + tid;
    if (n < N_NODES) rowp[n] = base + ex;
    __syncthreads();
    lcnt[tid] = 0;
    __syncthreads();
    for (int i = tid; i < cntb; i += 256) {
        uint2 v = reg[i];
        int dloc = (v.x >> 16) & 255;
        int pos = lofs[dloc] + atomicAdd(&lcnt[dloc], 1);
        // pack: src (16b) | bf16(ea) (16b).  dst implied by position.
        esrt[pos] = (v.x & 0xFFFFu) | ((v.y + 0x8000u) & 0xFFFF0000u);
    }
}

// ---------------- fused GAT layer: online softmax + 4-deep float4 gathers ----------
__global__ __launch_bounds__(256) void k_fused(const int* __restrict__ rowp,
                                               const unsigned* __restrict__ esrt,
                                               const float* __restrict__ asrc,
                                               const float* __restrict__ adst,
                                               const float* __restrict__ hs,
                                               const float* __restrict__ cbuf,
                                               int layer,
                                               const float* __restrict__ gbias,
                                               float* __restrict__ hout) {
    int wid = (blockIdx.x * 256 + threadIdx.x) >> 6;
    int lane = threadIdx.x & 63;
    if (wid >= N_NODES) return;
    int beg = rowp[wid], end = rowp[wid + 1];
    float adv = adst[wid];
    float c = cbuf[layer];
    float m = -INFINITY, sum = 0.f;
    float4 acc = make_float4(0.f, 0.f, 0.f, 0.f);
    int g = lane >> 4, fl = lane & 15;
    const float4* hs4 = (const float4*)hs;

    for (int base = beg; base < end; base += 64) {
        int idx = base + lane;
        bool ok = idx < end;
        unsigned v = ok ? esrt[idx] : 0u;
        int s = v & 0xFFFF;
        float a;
        if (ok) {
            float eav = __uint_as_float(v & 0xFFFF0000u);
            a = asrc[s] + adv + c * eav;
            a = a >= 0.f ? a : 0.2f * a;
        } else {
            a = -INFINITY;
        }
        float cm = a;
        #pragma unroll
        for (int o = 1; o < 64; o <<= 1) cm = fmaxf(cm, __shfl_xor(cm, o));
        float newm = fmaxf(m, cm);
        float scale = __expf(m - newm);   // 0 on first chunk (m=-inf)
        sum *= scale;
        acc.x *= scale; acc.y *= scale; acc.z *= scale; acc.w *= scale;
        m = newm;
        float ex = ok ? __expf(a - m) : 0.f;
        float cs = ex;
        #pragma unroll
        for (int o = 1; o < 64; o <<= 1) cs += __shfl_xor(cs, o);
        sum += cs;

        int lim = end - base; if (lim > 64) lim = 64;
        // 4 groups of 16 lanes, one edge per group per slot, float4 per lane;
        // 4-deep unroll -> 16 independent 256B gathers in flight per wave.
        int t = g;
        for (; t + 12 < lim; t += 16) {
            float w0 = __shfl(ex, t),      w1 = __shfl(ex, t + 4);
            float w2 = __shfl(ex, t + 8),  w3 = __shfl(ex, t + 12);
            int   s0 = __shfl(s, t),       s1 = __shfl(s, t + 4);
            int   s2 = __shfl(s, t + 8),   s3 = __shfl(s, t + 12);
            float4 r0 = hs4[s0 * 16 + fl];
            float4 r1 = hs4[s1 * 16 + fl];
            float4 r2 = hs4[s2 * 16 + fl];
            float4 r3 = hs4[s3 * 16 + fl];
            acc.x += w0 * r0.x; acc.y += w0 * r0.y; acc.z += w0 * r0.z; acc.w += w0 * r0.w;
            acc.x += w1 * r1.x; acc.y += w1 * r1.y; acc.z += w1 * r1.z; acc.w += w1 * r1.w;
            acc.x += w2 * r2.x; acc.y += w2 * r2.y; acc.z += w2 * r2.z; acc.w += w2 * r2.w;
            acc.x += w3 * r3.x; acc.y += w3 * r3.y; acc.z += w3 * r3.z; acc.w += w3 * r3.w;
        }
        for (; t < lim; t += 4) {
            float w0 = __shfl(ex, t);
            int   s0 = __shfl(s, t);
            float4 r0 = hs4[s0 * 16 + fl];
            acc.x += w0 * r0.x; acc.y += w0 * r0.y; acc.z += w0 * r0.z; acc.w += w0 * r0.w;
        }
    }
    // reduce the 4 group accumulators
    acc.x += __shfl_xor(acc.x, 16); acc.y += __shfl_xor(acc.y, 16);
    acc.z += __shfl_xor(acc.z, 16); acc.w += __shfl_xor(acc.w, 16);
    acc.x += __shfl_xor(acc.x, 32); acc.y += __shfl_xor(acc.y, 32);
    acc.z += __shfl_xor(acc.z, 32); acc.w += __shfl_xor(acc.w, 32);

    if (lane < 16) {
        float inv = 1.f / (sum + 1e-16f);
        float4 gb = ((const float4*)(gbias + layer * H_DIM))[lane];
        float4 val;
        val.x = acc.x * inv + gb.x; val.x = val.x > 0.f ? val.x : 0.f;
        val.y = acc.y * inv + gb.y; val.y = val.y > 0.f ? val.y : 0.f;
        val.z = acc.z * inv + gb.z; val.z = val.z > 0.f ? val.z : 0.f;
        val.w = acc.w * inv + gb.w; val.w = val.w > 0.f ? val.w : 0.f;
        ((float4*)(hout + (size_t)wid * H_DIM))[lane] = val;
    }
}

// ---------------- pooling: partial sums, 32 blocks per graph ----------------
__global__ __launch_bounds__(256) void k_pool(const float* __restrict__ h,
                                              float* __restrict__ gsum) {
    int g = blockIdx.x / POOL_CHUNKS;
    int chunk = blockIdx.x % POOL_CHUNKS;
    int wave = threadIdx.x >> 6, lane = threadIdx.x & 63;
    const int per_chunk = (NODES_PER_GRAPH + POOL_CHUNKS - 1) / POOL_CHUNKS;
    int n0 = g * NODES_PER_GRAPH + chunk * per_chunk;
    int n1 = g * NODES_PER_GRAPH + min((chunk + 1) * per_chunk, NODES_PER_GRAPH);
    float sum = 0.f;
    for (int n = n0 + wave; n < n1; n += 4)
        sum += h[(size_t)n * H_DIM + lane];
    __shared__ float spart[4][64];
    spart[wave][lane] = sum;
    __syncthreads();
    if (wave == 0) {
        float tot = spart[0][lane] + spart[1][lane] + spart[2][lane] + spart[3][lane];
        atomicAdd(gsum + g * H_DIM + lane, tot);
    }
}

// ---------------- head MLP: one wave per graph ----------------
__global__ __launch_bounds__(64) void k_head2(const float* __restrict__ gsum,
                                              const float* __restrict__ gf,
                                              const float* __restrict__ Wg,
                                              const float* __restrict__ bg,
                                              const float* __restrict__ Wc,
                                              const float* __restrict__ bc,
                                              const float* __restrict__ Wo,
                                              const float* __restrict__ bo,
                                              float* __restrict__ out) {
    int g = blockIdx.x;
    int lane = threadIdx.x;
    __shared__ float sgraph[64];
    __shared__ float sgf[64];
    sgraph[lane] = gsum[g * H_DIM + lane] / (float)NODES_PER_GRAPH;
    float gv = bg[lane];
    #pragma unroll
    for (int k = 0; k < 6; ++k) gv += gf[g * 6 + k] * Wg[k * 64 + lane];
    sgf[lane] = gv;
    __syncthreads();
    float cj = bc[lane];
    #pragma unroll
    for (int k = 0; k < 64; ++k) cj += sgraph[k] * Wc[k * 64 + lane];
    #pragma unroll
    for (int k = 0; k < 64; ++k) cj += sgf[k] * Wc[(64 + k) * 64 + lane];
    cj = cj > 0.f ? cj : 0.f;
    float o = cj * Wo[lane];
    #pragma unroll
    for (int m = 1; m < 64; m <<= 1) o += __shfl_xor(o, m);
    if (lane == 0) out[g] = o + bo[0];
}

extern "C" void kernel_launch(void* const* d_in, const int* in_sizes, int n_in,
                              void* d_out, int out_size, void* d_ws, size_t ws_size,
                              hipStream_t stream) {
    const float* x        = (const float*)d_in[0];
    const float* ea       = (const float*)d_in[1];
    const float* gf       = (const float*)d_in[2];
    const int*   ei       = (const int*)d_in[3];
    const float* W_embed  = (const float*)d_in[5];
    const float* b_embed  = (const float*)d_in[6];
    const float* W_glob   = (const float*)d_in[7];
    const float* b_glob   = (const float*)d_in[8];
    const float* lin_W    = (const float*)d_in[9];
    const float* att_src  = (const float*)d_in[10];
    const float* att_dst  = (const float*)d_in[11];
    const float* lin_eW   = (const float*)d_in[12];
    const float* att_edge = (const float*)d_in[13];
    const float* gat_bias = (const float*)d_in[14];
    const float* W_comb   = (const float*)d_in[15];
    const float* b_comb   = (const float*)d_in[16];
    const float* W_out    = (const float*)d_in[17];
    const float* b_out    = (const float*)d_in[18];
    float* out = (float*)d_out;
    float* ws  = (float*)d_ws;

    float*    h      = ws + OFF_H;
    float*    hs     = ws + OFF_HS;
    uint2*    stage  = (uint2*)(ws + OFF_HS);   // aliased: consumed before hs written
    float*    asrc   = ws + OFF_ASRC;
    float*    adst   = ws + OFF_ADST;
    float*    cbuf   = ws + OFF_CBUF;
    int*      bcur   = (int*)(ws + OFF_BCUR);
    float*    gsum   = ws + OFF_GSUM;
    int*      bbase  = (int*)(ws + OFF_BBASE);
    int*      rowp   = (int*)(ws + OFF_ROWP);
    unsigned* esrt   = (unsigned*)(ws + OFF_ESRT);

    hipMemsetAsync(ws + OFF_ZERO, 0, (size_t)(OFF_ZEND - OFF_ZERO) * sizeof(float), stream);
    k_embed<<<2560, 256, 0, stream>>>(x, W_embed, b_embed, h);

    // CSR by dst: two-level binned counting sort (no global per-node atomics)
    k_bin<<<NB_BIN, 256, 0, stream>>>(ei, ea, stage, bcur);
    k_bscan<<<1, 256, 0, stream>>>(bcur, bbase, rowp, lin_eW, att_edge, cbuf);
    k_group<<<NBUCK, 256, 0, stream>>>(stage, bcur, bbase, rowp, esrt);

    for (int l = 0; l < 2; ++l) {
        k_hs<<<2560, 256, 0, stream>>>(h, lin_W + l * 64 * 64,
                                       att_src + l * 64, att_dst + l * 64,
                                       hs, asrc, adst);
        k_fused<<<(N_NODES + 3) / 4, 256, 0, stream>>>(rowp, esrt,
                                                       asrc, adst, hs, cbuf, l,
                                                       gat_bias, h);
    }

    k_pool<<<N_GRAPH * POOL_CHUNKS, 256, 0, stream>>>(h, gsum);
    k_head2<<<N_GRAPH, 64, 0, stream>>>(gsum, gf, W_glob, b_glob,
                                        W_comb, b_comb, W_out, b_out, out);
}